// Round 8
// baseline (159.885 us; speedup 1.0000x reference)
//
#include <hip/hip_runtime.h>
#include <hip/hip_bf16.h>
#include <math.h>

#define DIN 512
#define TT  512

using bf16x8 = __attribute__((ext_vector_type(8))) short;
using f32x4  = __attribute__((ext_vector_type(4))) float;

static __device__ __forceinline__ unsigned short f2bf(float x) {
    __hip_bfloat16 h = __float2bfloat16(x);
    return *reinterpret_cast<unsigned short*>(&h);
}
static __device__ __forceinline__ unsigned int pack2(float a, float b) {
    return (unsigned int)f2bf(a) | ((unsigned int)f2bf(b) << 16);
}

// ws layout: Pgb bf16 [4 bg][32 p][512 s], qb f32 [128], flags int[128], ctr int[1].
// P/qb pre-scaled by 0.125.

__global__ __launch_bounds__(512) void pk_kernel(const float* __restrict__ Q,
                                                 const float* __restrict__ Wk,
                                                 const float* __restrict__ bk,
                                                 unsigned short* __restrict__ Pgb,
                                                 float* __restrict__ qb,
                                                 int* __restrict__ flags,
                                                 int* __restrict__ ctr) {
    const int bid = blockIdx.x;   // [0,128) = bg*32 + p
    const int bg = bid >> 5;
    const int p  = bid & 31;
    const int h  = p >> 2;
    const int ua = p & 3;
    const int a_q = h >> 1;
    const int h_q = (4 * h + bg) & 7;
    const int ch_base = ua * 512 + h * 64;

    __shared__ float qv[64];
    const int tid = threadIdx.x;
    if (tid < 64) qv[tid] = Q[(a_q * 8 + h_q) * 64 + tid];
    if (tid == 0) {               // re-init sync state every call (graph-replay safe)
        flags[bid] = 0;
        if (bid == 0) *ctr = 0;
    }
    __syncthreads();

    const int s = tid;
    float acc = 0.f;
    #pragma unroll 8
    for (int d = 0; d < 64; ++d)
        acc += qv[d] * Wk[(size_t)(ch_base + d) * DIN + s];
    Pgb[(size_t)(bg * 32 + p) * 512 + s] = f2bf(acc * 0.125f);

    if (tid == 0) {
        float sum = 0.f;
        for (int d = 0; d < 64; ++d) sum += qv[d] * bk[ch_base + d];
        qb[bg * 32 + p] = sum * 0.125f;
    }
}

// Persistent work-queue kernel. Items 0..511: score tile (b = it>>2, j = it&3).
// Items 512..1535: pv tile (b = t>>3, h = t&7). pv waits on flags[b] == 4.
__global__ __launch_bounds__(256, 3) void persist_kernel(
        const float* __restrict__ v,
        const unsigned short* __restrict__ Pgb,
        const float* __restrict__ qb,
        float* __restrict__ attn,
        float* __restrict__ out,
        int* __restrict__ flags,
        int* __restrict__ ctr)
{
    __shared__ __align__(16) char smem[34816];
    __shared__ int s_item;
    const int tid  = threadIdx.x;
    const int lane = tid & 63;
    const int w    = tid >> 6;

    for (;;) {
        __syncthreads();                      // protect smem + s_item reuse
        if (tid == 0) s_item = atomicAdd(ctr, 1);
        __syncthreads();
        const int item = s_item;
        if (item >= 1536) break;

        if (item < 512) {
            // ================= SCORE (b, j) =================
            const int b = item >> 2;
            const int j = item & 3;
            const int bg = b >> 5;

            char* vt[2] = { smem, smem + 10240 };              // [128 rows][32 k] bf16, 80 B stride
            float (*red2)[2][4][2] = reinterpret_cast<float (*)[2][4][2]>(smem + 20480);

            const float* vbase = v + ((size_t)b * TT + j * 128) * DIN;
            const int srow  = tid >> 1;
            const int shalf = tid & 1;
            const float* vsrc = vbase + (size_t)srow * DIN + shalf * 16;
            const int vdo = srow * 80 + shalf * 32;

            const unsigned short* pb0 = Pgb + ((size_t)(bg * 32) + (lane & 15)) * 512 + (lane >> 4) * 8;
            const unsigned short* pb1 = pb0 + 16 * 512;

            const int akb  = (lane >> 4) * 16;
            const int aoff = (w * 32 + (lane & 15)) * 80 + akb;

            const float qv0 = qb[bg * 32 + (lane & 15)];
            const float qv1 = qb[bg * 32 + 16 + (lane & 15)];

            f32x4 acc[2][2];
            #pragma unroll
            for (int i = 0; i < 2; ++i)
                #pragma unroll
                for (int n = 0; n < 2; ++n)
                    #pragma unroll
                    for (int r = 0; r < 4; ++r) acc[i][n][r] = 0.f;

            float4 vrA[4], vrB[4];
            bf16x8 brA0, brA1, brB0, brB1;
            #pragma unroll
            for (int q = 0; q < 4; ++q) vrA[q] = *(const float4*)(vsrc + q * 4);
            brA0 = *(const bf16x8*)(pb0);
            brA1 = *(const bf16x8*)(pb1);
            {
                uint4 lo, hi;
                lo.x = pack2(vrA[0].x, vrA[0].y); lo.y = pack2(vrA[0].z, vrA[0].w);
                lo.z = pack2(vrA[1].x, vrA[1].y); lo.w = pack2(vrA[1].z, vrA[1].w);
                hi.x = pack2(vrA[2].x, vrA[2].y); hi.y = pack2(vrA[2].z, vrA[2].w);
                hi.z = pack2(vrA[3].x, vrA[3].y); hi.w = pack2(vrA[3].z, vrA[3].w);
                *(uint4*)(vt[0] + vdo)      = lo;
                *(uint4*)(vt[0] + vdo + 16) = hi;
            }
            __syncthreads();

#define STEP(CUR, VRN, BRC0, BRC1, BRN0, BRN1, KT)                            \
    {                                                                         \
        if ((KT) + 1 < 16) {                                                  \
            const float* vn = vsrc + ((KT) + 1) * 32;                         \
            VRN[0] = *(const float4*)(vn);                                    \
            VRN[1] = *(const float4*)(vn + 4);                                \
            VRN[2] = *(const float4*)(vn + 8);                                \
            VRN[3] = *(const float4*)(vn + 12);                               \
            BRN0 = *(const bf16x8*)(pb0 + ((KT) + 1) * 32);                   \
            BRN1 = *(const bf16x8*)(pb1 + ((KT) + 1) * 32);                   \
        }                                                                     \
        bf16x8 a0 = *(const bf16x8*)(vt[CUR] + aoff);                         \
        bf16x8 a1 = *(const bf16x8*)(vt[CUR] + aoff + 16 * 80);               \
        acc[0][0] = __builtin_amdgcn_mfma_f32_16x16x32_bf16(a0, BRC0, acc[0][0], 0, 0, 0); \
        acc[0][1] = __builtin_amdgcn_mfma_f32_16x16x32_bf16(a0, BRC1, acc[0][1], 0, 0, 0); \
        acc[1][0] = __builtin_amdgcn_mfma_f32_16x16x32_bf16(a1, BRC0, acc[1][0], 0, 0, 0); \
        acc[1][1] = __builtin_amdgcn_mfma_f32_16x16x32_bf16(a1, BRC1, acc[1][1], 0, 0, 0); \
        if ((KT) + 1 < 16) {                                                  \
            uint4 lo, hi;                                                     \
            lo.x = pack2(VRN[0].x, VRN[0].y); lo.y = pack2(VRN[0].z, VRN[0].w); \
            lo.z = pack2(VRN[1].x, VRN[1].y); lo.w = pack2(VRN[1].z, VRN[1].w); \
            hi.x = pack2(VRN[2].x, VRN[2].y); hi.y = pack2(VRN[2].z, VRN[2].w); \
            hi.z = pack2(VRN[3].x, VRN[3].y); hi.w = pack2(VRN[3].z, VRN[3].w); \
            *(uint4*)(vt[(CUR) ^ 1] + vdo)      = lo;                         \
            *(uint4*)(vt[(CUR) ^ 1] + vdo + 16) = hi;                         \
        }                                                                     \
        __syncthreads();                                                      \
    }

            for (int kt = 0; kt < 16; kt += 2) {
                STEP(0, vrB, brA0, brA1, brB0, brB1, kt)
                STEP(1, vrA, brB0, brB1, brA0, brA1, kt + 1)
            }
#undef STEP

            float lg[2][8];
            #pragma unroll
            for (int i = 0; i < 2; ++i)
                #pragma unroll
                for (int r = 0; r < 4; ++r) {
                    lg[0][i * 4 + r] = acc[i][0][r] + qv0;
                    lg[1][i * 4 + r] = acc[i][1][r] + qv1;
                }

            const int hsub = (lane >> 2) & 3;
            float mw[2], sw[2], ev[2][8];
            #pragma unroll
            for (int nt = 0; nt < 2; ++nt) {
                float m = lg[nt][0];
                #pragma unroll
                for (int q = 1; q < 8; ++q) m = fmaxf(m, lg[nt][q]);
                m = fmaxf(m, __shfl_xor(m, 1));
                m = fmaxf(m, __shfl_xor(m, 2));
                m = fmaxf(m, __shfl_xor(m, 16));
                m = fmaxf(m, __shfl_xor(m, 32));
                float s = 0.f;
                #pragma unroll
                for (int q = 0; q < 8; ++q) { ev[nt][q] = __expf(lg[nt][q] - m); s += ev[nt][q]; }
                s += __shfl_xor(s, 1);
                s += __shfl_xor(s, 2);
                s += __shfl_xor(s, 16);
                s += __shfl_xor(s, 32);
                mw[nt] = m; sw[nt] = s;
            }
            if ((lane & 0x33) == 0) {
                #pragma unroll
                for (int nt = 0; nt < 2; ++nt) {
                    red2[w][nt][hsub][0] = mw[nt];
                    red2[w][nt][hsub][1] = sw[nt];
                }
            }
            __syncthreads();

            #pragma unroll
            for (int nt = 0; nt < 2; ++nt) {
                float M = red2[0][nt][hsub][0];
                M = fmaxf(M, red2[1][nt][hsub][0]);
                M = fmaxf(M, red2[2][nt][hsub][0]);
                M = fmaxf(M, red2[3][nt][hsub][0]);
                float S = 0.f;
                #pragma unroll
                for (int w2 = 0; w2 < 4; ++w2)
                    S += __expf(red2[w2][nt][hsub][0] - M) * red2[w2][nt][hsub][1];
                const float factor = __expf(mw[nt] - M) / S;

                const int h = nt * 4 + hsub;
                float* arow = attn + ((size_t)(h * 512 + b * 4 + j)) * 512;
                const int ua = lane & 3;
                #pragma unroll
                for (int i = 0; i < 2; ++i)
                    #pragma unroll
                    for (int r = 0; r < 4; ++r) {
                        const int trow = w * 32 + i * 16 + ((lane >> 4) & 3) * 4 + r;
                        arow[trow * 4 + ua] = ev[nt][i * 4 + r] * factor;
                    }
            }

            __syncthreads();   // all attn stores drained (barrier implies vmcnt(0))
            if (tid == 0)
                __hip_atomic_fetch_add(flags + b, 1, __ATOMIC_RELEASE, __HIP_MEMORY_SCOPE_AGENT);

        } else {
            // ================= PV (b, h) =================
            const int t = item - 512;
            const int b = t >> 3;
            const int h = t & 7;

            if (tid == 0) {
                while (__hip_atomic_load(flags + b, __ATOMIC_ACQUIRE, __HIP_MEMORY_SCOPE_AGENT) < 4)
                    __builtin_amdgcn_s_sleep(2);
            }
            __syncthreads();

            float (*at)[512]    = reinterpret_cast<float (*)[512]>(smem);    // [4][512]
            float (*red)[4][68] = reinterpret_cast<float (*)[4][68]>(smem);  // [32][4][68]

            {
                const int jj = tid >> 6;
                const int u8 = (tid & 63) * 8;
                const float* src = attn + ((size_t)(h * 512 + b * 4 + jj)) * 512 + u8;
                *(float4*)&at[jj][u8]     = *(const float4*)(src);
                *(float4*)&at[jj][u8 + 4] = *(const float4*)(src + 4);
            }
            __syncthreads();

            const int cg = tid & 7;
            const int up = tid >> 3;
            const int c8 = cg * 8;
            const float* vb = v + (size_t)b * TT * DIN + h * 64 + c8;

            float acc[4][8];
            #pragma unroll
            for (int jj = 0; jj < 4; ++jj)
                #pragma unroll
                for (int ci = 0; ci < 8; ++ci) acc[jj][ci] = 0.f;

            float4 r0 = *(const float4*)(vb + (size_t)up * DIN);
            float4 r1 = *(const float4*)(vb + (size_t)up * DIN + 4);

            for (int it2 = 0; it2 < 16; ++it2) {
                const int u = it2 * 32 + up;
                const float4 c0 = r0;
                const float4 c1 = r1;
                if (it2 < 15) {
                    const float* pn = vb + (size_t)(u + 32) * DIN;
                    r0 = *(const float4*)(pn);
                    r1 = *(const float4*)(pn + 4);
                }
                const float a0 = at[0][u];
                const float a1 = at[1][u];
                const float a2 = at[2][u];
                const float a3 = at[3][u];
                acc[0][0] += a0 * c0.x; acc[0][1] += a0 * c0.y; acc[0][2] += a0 * c0.z; acc[0][3] += a0 * c0.w;
                acc[0][4] += a0 * c1.x; acc[0][5] += a0 * c1.y; acc[0][6] += a0 * c1.z; acc[0][7] += a0 * c1.w;
                acc[1][0] += a1 * c0.x; acc[1][1] += a1 * c0.y; acc[1][2] += a1 * c0.z; acc[1][3] += a1 * c0.w;
                acc[1][4] += a1 * c1.x; acc[1][5] += a1 * c1.y; acc[1][6] += a1 * c1.z; acc[1][7] += a1 * c1.w;
                acc[2][0] += a2 * c0.x; acc[2][1] += a2 * c0.y; acc[2][2] += a2 * c0.z; acc[2][3] += a2 * c0.w;
                acc[2][4] += a2 * c1.x; acc[2][5] += a2 * c1.y; acc[2][6] += a2 * c1.z; acc[2][7] += a2 * c1.w;
                acc[3][0] += a3 * c0.x; acc[3][1] += a3 * c0.y; acc[3][2] += a3 * c0.z; acc[3][3] += a3 * c0.w;
                acc[3][4] += a3 * c1.x; acc[3][5] += a3 * c1.y; acc[3][6] += a3 * c1.z; acc[3][7] += a3 * c1.w;
            }

            __syncthreads();   // at[] dead; red aliases it

            #pragma unroll
            for (int jj = 0; jj < 4; ++jj) {
                float4 w0, w1;
                w0.x = acc[jj][0]; w0.y = acc[jj][1]; w0.z = acc[jj][2]; w0.w = acc[jj][3];
                w1.x = acc[jj][4]; w1.y = acc[jj][5]; w1.z = acc[jj][6]; w1.w = acc[jj][7];
                *(float4*)&red[up][jj][c8]     = w0;
                *(float4*)&red[up][jj][c8 + 4] = w1;
            }
            __syncthreads();

            const int jo = tid >> 6;
            const int c  = tid & 63;
            float s = 0.f;
            #pragma unroll
            for (int r2 = 0; r2 < 32; ++r2) s += red[r2][jo][c];
            out[((size_t)(h * 512 + b * 4 + jo)) * 64 + c] = s;
        }
    }
}

extern "C" void kernel_launch(void* const* d_in, const int* in_sizes, int n_in,
                              void* d_out, int out_size, void* d_ws, size_t ws_size,
                              hipStream_t stream) {
    const float* v  = (const float*)d_in[0];
    const float* Q  = (const float*)d_in[1];
    const float* Wk = (const float*)d_in[2];
    const float* bk = (const float*)d_in[3];

    float* out  = (float*)d_out;               // 4096*64
    float* attn = out + 4096 * 64;             // 4096*512

    unsigned short* Pgb = (unsigned short*)d_ws;     // 4*32*512 bf16
    float* qb  = (float*)(Pgb + 4 * 32 * 512);       // 128 f32
    int* flags = (int*)(qb + 128);                   // 128 ints
    int* ctr   = flags + 128;                        // 1 int

    pk_kernel<<<128, 512, 0, stream>>>(Q, Wk, bk, Pgb, qb, flags, ctr);
    persist_kernel<<<1024, 256, 0, stream>>>(v, Pgb, qb, attn, out, flags, ctr);
}

// Round 9
// 70.702 us; speedup vs baseline: 2.2614x; 2.2614x over previous
//
#include <hip/hip_runtime.h>
#include <hip/hip_bf16.h>
#include <math.h>

#define DIN 512
#define TT  512

using bf16x8 = __attribute__((ext_vector_type(8))) short;
using f32x4  = __attribute__((ext_vector_type(4))) float;

static __device__ __forceinline__ unsigned short f2bf(float x) {
    __hip_bfloat16 h = __float2bfloat16(x);
    return *reinterpret_cast<unsigned short*>(&h);
}
static __device__ __forceinline__ unsigned int pack2(float a, float b) {
    return (unsigned int)f2bf(a) | ((unsigned int)f2bf(b) << 16);
}

// ws layout: Pgb bf16 [4 bg][32 p][512 s], qb f32 [128]. Pre-scaled by 0.125.

__global__ __launch_bounds__(512) void pk_kernel(const float* __restrict__ Q,
                                                 const float* __restrict__ Wk,
                                                 const float* __restrict__ bk,
                                                 unsigned short* __restrict__ Pgb,
                                                 float* __restrict__ qb) {
    const int bid = blockIdx.x;   // [0,128) = bg*32 + p
    const int bg = bid >> 5;
    const int p  = bid & 31;
    const int h  = p >> 2;
    const int ua = p & 3;
    const int a_q = h >> 1;
    const int h_q = (4 * h + bg) & 7;
    const int ch_base = ua * 512 + h * 64;

    __shared__ float qv[64];
    const int tid = threadIdx.x;
    if (tid < 64) qv[tid] = Q[(a_q * 8 + h_q) * 64 + tid];
    __syncthreads();

    const int s = tid;
    float acc = 0.f;
    #pragma unroll 8
    for (int d = 0; d < 64; ++d)
        acc += qv[d] * Wk[(size_t)(ch_base + d) * DIN + s];
    Pgb[(size_t)(bg * 32 + p) * 512 + s] = f2bf(acc * 0.125f);

    if (tid == 0) {
        float sum = 0.f;
        for (int d = 0; d < 64; ++d) sum += qv[d] * bk[ch_base + d];
        qb[bg * 32 + p] = sum * 0.125f;
    }
}

// Combined kernel. Blocks [0, n_sc): SCORE tile (b = sc_b0 + i>>2, j = i&3) — r4 path.
// Blocks [n_sc, n_sc+n_pv): PV tile (b = pv_b0 + i>>3, h = i&7) — r4 path.
// Dependencies satisfied by stream order of dispatches (pv reads prev dispatch's attn).
__global__ __launch_bounds__(256) void combined_kernel(
        const float* __restrict__ v,
        const unsigned short* __restrict__ Pgb,
        const float* __restrict__ qb,
        float* __restrict__ attn,
        float* __restrict__ out,
        int sc_b0, int n_sc, int pv_b0)
{
    __shared__ __align__(16) char smem[43776];
    const int tid  = threadIdx.x;

    if ((int)blockIdx.x < n_sc) {
        // ================= SCORE (b, j) =================
        const int item = blockIdx.x;
        const int b = sc_b0 + (item >> 2);
        const int j = item & 3;
        const int bg = b >> 5;
        const int lane = tid & 63;
        const int w = tid >> 6;

        char* VtB = smem;                         // [128 rows][32 k] bf16, 80 B stride
        char* PtB = smem + 10240;                 // [32 p][512 k] bf16, 1040 B stride
        float (*red2)[2][4][2] = reinterpret_cast<float (*)[2][4][2]>(smem + 43520);

        const float* vbase = v + ((size_t)b * TT + j * 128) * DIN;

        {   // stage full P (bf16) once: 32 KB
            const int p  = tid >> 3;
            const int sg = tid & 7;
            const uint4* src = (const uint4*)(Pgb + ((size_t)(bg * 32 + p) * 512)) + sg * 8;
            uint4* dst = (uint4*)(PtB + p * 1040 + sg * 128);
            #pragma unroll
            for (int q = 0; q < 8; ++q) dst[q] = src[q];
        }

        const float qv0 = qb[bg * 32 + (lane & 15)];
        const float qv1 = qb[bg * 32 + 16 + (lane & 15)];

        f32x4 acc[2][2];
        #pragma unroll
        for (int i = 0; i < 2; ++i)
            #pragma unroll
            for (int n = 0; n < 2; ++n)
                #pragma unroll
                for (int r = 0; r < 4; ++r) acc[i][n][r] = 0.f;

        const int srow  = tid >> 1;
        const int shalf = tid & 1;
        const float* vsrc = vbase + (size_t)srow * DIN + shalf * 16;
        char* vdst = VtB + srow * 80 + shalf * 32;

        const int akb = (lane >> 4) * 16;
        const char* aptr  = VtB + (w * 32 + (lane & 15)) * 80 + akb;
        const char* bptr0 = PtB + ((lane & 15)) * 1040 + akb;
        const char* bptr1 = PtB + (16 + (lane & 15)) * 1040 + akb;

        float4 vrA[4], vrB[4];
        #pragma unroll
        for (int q = 0; q < 4; ++q) vrA[q] = *(const float4*)(vsrc + q * 4);
        #pragma unroll
        for (int q = 0; q < 4; ++q) vrB[q] = *(const float4*)(vsrc + 32 + q * 4);

#define SCORE_STEP(VR, KT)                                                    \
    {                                                                         \
        uint4 lo, hi;                                                         \
        lo.x = pack2(VR[0].x, VR[0].y); lo.y = pack2(VR[0].z, VR[0].w);       \
        lo.z = pack2(VR[1].x, VR[1].y); lo.w = pack2(VR[1].z, VR[1].w);       \
        hi.x = pack2(VR[2].x, VR[2].y); hi.y = pack2(VR[2].z, VR[2].w);       \
        hi.z = pack2(VR[3].x, VR[3].y); hi.w = pack2(VR[3].z, VR[3].w);       \
        *(uint4*)(vdst)      = lo;                                            \
        *(uint4*)(vdst + 16) = hi;                                            \
        __syncthreads();                                                      \
        if ((KT) < 14) {                                                      \
            const float* vn = vsrc + ((KT) + 2) * 32;                         \
            VR[0] = *(const float4*)(vn);                                     \
            VR[1] = *(const float4*)(vn + 4);                                 \
            VR[2] = *(const float4*)(vn + 8);                                 \
            VR[3] = *(const float4*)(vn + 12);                                \
        }                                                                     \
        const int ksb = (KT) * 64;                                            \
        bf16x8 a0 = *(const bf16x8*)(aptr);                                   \
        bf16x8 a1 = *(const bf16x8*)(aptr + 16 * 80);                         \
        bf16x8 b0 = *(const bf16x8*)(bptr0 + ksb);                            \
        bf16x8 b1 = *(const bf16x8*)(bptr1 + ksb);                            \
        acc[0][0] = __builtin_amdgcn_mfma_f32_16x16x32_bf16(a0, b0, acc[0][0], 0, 0, 0); \
        acc[0][1] = __builtin_amdgcn_mfma_f32_16x16x32_bf16(a0, b1, acc[0][1], 0, 0, 0); \
        acc[1][0] = __builtin_amdgcn_mfma_f32_16x16x32_bf16(a1, b0, acc[1][0], 0, 0, 0); \
        acc[1][1] = __builtin_amdgcn_mfma_f32_16x16x32_bf16(a1, b1, acc[1][1], 0, 0, 0); \
        __syncthreads();                                                      \
    }

        for (int kt = 0; kt < 16; kt += 2) {
            SCORE_STEP(vrA, kt);
            SCORE_STEP(vrB, kt + 1);
        }
#undef SCORE_STEP

        float lg[2][8];
        #pragma unroll
        for (int i = 0; i < 2; ++i)
            #pragma unroll
            for (int r = 0; r < 4; ++r) {
                lg[0][i * 4 + r] = acc[i][0][r] + qv0;
                lg[1][i * 4 + r] = acc[i][1][r] + qv1;
            }

        const int hsub = (lane >> 2) & 3;
        float mw[2], sw[2], ev[2][8];
        #pragma unroll
        for (int nt = 0; nt < 2; ++nt) {
            float m = lg[nt][0];
            #pragma unroll
            for (int q = 1; q < 8; ++q) m = fmaxf(m, lg[nt][q]);
            m = fmaxf(m, __shfl_xor(m, 1));
            m = fmaxf(m, __shfl_xor(m, 2));
            m = fmaxf(m, __shfl_xor(m, 16));
            m = fmaxf(m, __shfl_xor(m, 32));
            float s = 0.f;
            #pragma unroll
            for (int q = 0; q < 8; ++q) { ev[nt][q] = __expf(lg[nt][q] - m); s += ev[nt][q]; }
            s += __shfl_xor(s, 1);
            s += __shfl_xor(s, 2);
            s += __shfl_xor(s, 16);
            s += __shfl_xor(s, 32);
            mw[nt] = m; sw[nt] = s;
        }
        if ((lane & 0x33) == 0) {
            #pragma unroll
            for (int nt = 0; nt < 2; ++nt) {
                red2[w][nt][hsub][0] = mw[nt];
                red2[w][nt][hsub][1] = sw[nt];
            }
        }
        __syncthreads();

        #pragma unroll
        for (int nt = 0; nt < 2; ++nt) {
            float M = red2[0][nt][hsub][0];
            M = fmaxf(M, red2[1][nt][hsub][0]);
            M = fmaxf(M, red2[2][nt][hsub][0]);
            M = fmaxf(M, red2[3][nt][hsub][0]);
            float S = 0.f;
            #pragma unroll
            for (int w2 = 0; w2 < 4; ++w2)
                S += __expf(red2[w2][nt][hsub][0] - M) * red2[w2][nt][hsub][1];
            const float factor = __expf(mw[nt] - M) / S;

            const int h = nt * 4 + hsub;
            float* arow = attn + ((size_t)(h * 512 + b * 4 + j)) * 512;
            const int ua = lane & 3;
            #pragma unroll
            for (int i = 0; i < 2; ++i)
                #pragma unroll
                for (int r = 0; r < 4; ++r) {
                    const int trow = w * 32 + i * 16 + ((lane >> 4) & 3) * 4 + r;
                    arow[trow * 4 + ua] = ev[nt][i * 4 + r] * factor;
                }
        }

    } else {
        // ================= PV (b, h) =================
        const int item = blockIdx.x - n_sc;
        const int b = pv_b0 + (item >> 3);
        const int h = item & 7;

        float (*at)[512]    = reinterpret_cast<float (*)[512]>(smem);    // [4][512] = 8 KB
        float (*red)[4][68] = reinterpret_cast<float (*)[4][68]>(smem);  // [32][4][68]

        {
            const int jj = tid >> 6;
            const int u8 = (tid & 63) * 8;
            const float* src = attn + ((size_t)(h * 512 + b * 4 + jj)) * 512 + u8;
            *(float4*)&at[jj][u8]     = *(const float4*)(src);
            *(float4*)&at[jj][u8 + 4] = *(const float4*)(src + 4);
        }
        __syncthreads();

        const int cg = tid & 7;
        const int up = tid >> 3;
        const int c8 = cg * 8;
        const float* vb = v + (size_t)b * TT * DIN + h * 64 + c8;

        float acc[4][8];
        #pragma unroll
        for (int jj = 0; jj < 4; ++jj)
            #pragma unroll
            for (int ci = 0; ci < 8; ++ci) acc[jj][ci] = 0.f;

        float4 rA0 = *(const float4*)(vb + (size_t)up * DIN);
        float4 rA1 = *(const float4*)(vb + (size_t)up * DIN + 4);
        float4 rB0 = *(const float4*)(vb + (size_t)(up + 32) * DIN);
        float4 rB1 = *(const float4*)(vb + (size_t)(up + 32) * DIN + 4);

#define PV_STEP(R0, R1, IT)                                                   \
    {                                                                         \
        const int u = (IT) * 32 + up;                                         \
        const float4 c0 = R0;                                                 \
        const float4 c1 = R1;                                                 \
        if ((IT) < 14) {                                                      \
            const float* pn = vb + (size_t)(u + 64) * DIN;                    \
            R0 = *(const float4*)(pn);                                        \
            R1 = *(const float4*)(pn + 4);                                    \
        }                                                                     \
        const float a0 = at[0][u];                                            \
        const float a1 = at[1][u];                                            \
        const float a2 = at[2][u];                                            \
        const float a3 = at[3][u];                                            \
        acc[0][0] += a0 * c0.x; acc[0][1] += a0 * c0.y; acc[0][2] += a0 * c0.z; acc[0][3] += a0 * c0.w; \
        acc[0][4] += a0 * c1.x; acc[0][5] += a0 * c1.y; acc[0][6] += a0 * c1.z; acc[0][7] += a0 * c1.w; \
        acc[1][0] += a1 * c0.x; acc[1][1] += a1 * c0.y; acc[1][2] += a1 * c0.z; acc[1][3] += a1 * c0.w; \
        acc[1][4] += a1 * c1.x; acc[1][5] += a1 * c1.y; acc[1][6] += a1 * c1.z; acc[1][7] += a1 * c1.w; \
        acc[2][0] += a2 * c0.x; acc[2][1] += a2 * c0.y; acc[2][2] += a2 * c0.z; acc[2][3] += a2 * c0.w; \
        acc[2][4] += a2 * c1.x; acc[2][5] += a2 * c1.y; acc[2][6] += a2 * c1.z; acc[2][7] += a2 * c1.w; \
        acc[3][0] += a3 * c0.x; acc[3][1] += a3 * c0.y; acc[3][2] += a3 * c0.z; acc[3][3] += a3 * c0.w; \
        acc[3][4] += a3 * c1.x; acc[3][5] += a3 * c1.y; acc[3][6] += a3 * c1.z; acc[3][7] += a3 * c1.w; \
    }

        for (int it = 0; it < 16; it += 2) {
            PV_STEP(rA0, rA1, it);
            PV_STEP(rB0, rB1, it + 1);
        }
#undef PV_STEP

        __syncthreads();   // at[] dead beyond here; red aliases it

        #pragma unroll
        for (int jj = 0; jj < 4; ++jj) {
            float4 w0, w1;
            w0.x = acc[jj][0]; w0.y = acc[jj][1]; w0.z = acc[jj][2]; w0.w = acc[jj][3];
            w1.x = acc[jj][4]; w1.y = acc[jj][5]; w1.z = acc[jj][6]; w1.w = acc[jj][7];
            *(float4*)&red[up][jj][c8]     = w0;
            *(float4*)&red[up][jj][c8 + 4] = w1;
        }
        __syncthreads();

        const int jo = tid >> 6;
        const int c  = tid & 63;
        float s = 0.f;
        #pragma unroll
        for (int r2 = 0; r2 < 32; ++r2) s += red[r2][jo][c];
        out[((size_t)(h * 512 + b * 4 + jo)) * 64 + c] = s;
    }
}

extern "C" void kernel_launch(void* const* d_in, const int* in_sizes, int n_in,
                              void* d_out, int out_size, void* d_ws, size_t ws_size,
                              hipStream_t stream) {
    const float* v  = (const float*)d_in[0];
    const float* Q  = (const float*)d_in[1];
    const float* Wk = (const float*)d_in[2];
    const float* bk = (const float*)d_in[3];

    float* out  = (float*)d_out;               // 4096*64
    float* attn = out + 4096 * 64;             // 4096*512

    unsigned short* Pgb = (unsigned short*)d_ws;     // 4*32*512 bf16
    float* qb = (float*)(Pgb + 4 * 32 * 512);        // 128 f32

    pk_kernel<<<128, 512, 0, stream>>>(Q, Wk, bk, Pgb, qb);

    // Pipelined dispatches: dispatch k = score(group k) + pv(group k-1).
    // Groups of 32 b's: 128 score tiles, 256 pv tiles per group.
    combined_kernel<<<128, 256, 0, stream>>>(v, Pgb, qb, attn, out,  0, 128,  0);
    combined_kernel<<<384, 256, 0, stream>>>(v, Pgb, qb, attn, out, 32, 128,  0);
    combined_kernel<<<384, 256, 0, stream>>>(v, Pgb, qb, attn, out, 64, 128, 32);
    combined_kernel<<<384, 256, 0, stream>>>(v, Pgb, qb, attn, out, 96, 128, 64);
    combined_kernel<<<256, 256, 0, stream>>>(v, Pgb, qb, attn, out,  0,   0, 96);
}